// Round 4
// baseline (1422.035 us; speedup 1.0000x reference)
//
#include <hip/hip_runtime.h>

#define V 16000
#define E 256
#define H 512
#define BB 8      // batch = greedy rows
#define T 12      // lenseq
#define NB 256    // persistent blocks (one launch)
#define VPB 63    // vocab cols per block (256*63 >= 16000)

// Beam search degenerates to greedy (prob stays 1, beams identical, top_k
// tie-break keeps identity permutation, best_beam=0) -> 8 greedy decodes,
// pred written straight to out[t]. Verified by R3 pass (absmax 4.8e-7).
// R4: fuse all 12 steps into ONE persistent kernel with a device-scope grid
// barrier (2 per step); x/token state recomputed redundantly per block.

__device__ __forceinline__ float dot4(float4 a, float4 b) {
    return a.x * b.x + a.y * b.y + a.z * b.z + a.w * b.w;
}

__global__ __launch_bounds__(256) void kinit(const float* __restrict__ hidden,
                                             float* __restrict__ hA,
                                             int* __restrict__ bar) {
    int idx = blockIdx.x * 256 + threadIdx.x;
    if (idx < BB * H) hA[idx] = hidden[idx];
    if (idx < 2) bar[idx] = 0;
}

__device__ __forceinline__ void gridbar(int* bar) {
    __syncthreads();
    if (threadIdx.x == 0) {
        __threadfence();  // release: make this block's writes device-visible
        int g = __hip_atomic_load(&bar[1], __ATOMIC_RELAXED, __HIP_MEMORY_SCOPE_AGENT);
        int a = __hip_atomic_fetch_add(&bar[0], 1, __ATOMIC_ACQ_REL, __HIP_MEMORY_SCOPE_AGENT);
        if (a == NB - 1) {
            __hip_atomic_store(&bar[0], 0, __ATOMIC_RELAXED, __HIP_MEMORY_SCOPE_AGENT);
            __hip_atomic_fetch_add(&bar[1], 1, __ATOMIC_RELEASE, __HIP_MEMORY_SCOPE_AGENT);
        } else {
            while (__hip_atomic_load(&bar[1], __ATOMIC_RELAXED, __HIP_MEMORY_SCOPE_AGENT) == g)
                __builtin_amdgcn_s_sleep(1);
        }
        __threadfence();  // acquire: invalidate stale caches before reads
    }
    __syncthreads();
}

__global__ __launch_bounds__(256, 4) void kmain(
    const float* __restrict__ emb_tab,
    const float* __restrict__ w_ih,
    const float* __restrict__ w_hh,
    const float* __restrict__ b_ih,
    const float* __restrict__ b_hh,
    const float* __restrict__ w_out,
    const float* __restrict__ b_out,
    float* __restrict__ hA,
    float* __restrict__ hB,
    float* __restrict__ psum,
    float* __restrict__ pval,
    int* __restrict__ pidx,
    int* __restrict__ bar,
    float* __restrict__ out)
{
    const int blk = blockIdx.x, tid = threadIdx.x;

    __shared__ float s_part[64 * 24];   // phase A: 64 (j,r) pairs x 6 gates x 4 K-quarters
    __shared__ float s_v[256];
    __shared__ float s_av[256];
    __shared__ int   s_ai[256];
    __shared__ float s_S[BB];
    __shared__ int   s_Xn[BB];
    __shared__ int   s_X[BB];

    if (tid < BB) s_X[tid] = 1;         // SOS
    __syncthreads();

    // phase B/C thread mapping: row r = tid&7, two vocab cols per thread
    const int r   = tid & 7;
    const int vl0 = tid >> 3;           // 0..31
    const int vl1 = vl0 + 32;           // 32..63
    const int v_0 = blk * VPB + vl0;
    const int v_1 = blk * VPB + vl1;
    const bool ok0 = (v_0 < V);
    const bool ok1 = (vl1 < VPB) && (v_1 < V);

    float e0 = 0.f, e1 = 0.f;           // exp(logit), persists A->C in registers

    for (int t = 0; t < T; t++) {
        const float* h_cur = (t & 1) ? hB : hA;
        float*       h_nxt = (t & 1) ? hA : hB;

        // ---------- phase A: GRU cell, blocks 0..63, 4-way K split ----------
        if (blk < 64) {
            const int p  = tid >> 2;    // pair 0..63
            const int q  = tid & 3;     // K quarter
            const int jl = p >> 3;      // 0..7
            const int ar = p & 7;       // row
            const int j  = blk * 8 + jl;
            const int xr = s_X[ar];
            const float* erow = emb_tab + (size_t)xr * E;
            const float* hrow = h_cur + ar * H;
            float gir = 0.f, giz = 0.f, gin = 0.f, ghr = 0.f, ghz = 0.f, ghn = 0.f;
            {
                const float* w0 = w_ih + (size_t)j * E;
                const float* w1 = w0 + (size_t)H * E;
                const float* w2 = w1 + (size_t)H * E;
                const int k0 = q * (E / 4);
                for (int k = k0; k < k0 + E / 4; k += 4) {
                    float4 ev = *(const float4*)(erow + k);
                    gir += dot4(*(const float4*)(w0 + k), ev);
                    giz += dot4(*(const float4*)(w1 + k), ev);
                    gin += dot4(*(const float4*)(w2 + k), ev);
                }
            }
            {
                const float* w0 = w_hh + (size_t)j * H;
                const float* w1 = w0 + (size_t)H * H;
                const float* w2 = w1 + (size_t)H * H;
                const int k0 = q * (H / 4);
                for (int k = k0; k < k0 + H / 4; k += 4) {
                    float4 hv = *(const float4*)(hrow + k);
                    ghr += dot4(*(const float4*)(w0 + k), hv);
                    ghz += dot4(*(const float4*)(w1 + k), hv);
                    ghn += dot4(*(const float4*)(w2 + k), hv);
                }
            }
            float* sp = s_part + p * 24;
            sp[0 * 4 + q] = gir; sp[1 * 4 + q] = giz; sp[2 * 4 + q] = gin;
            sp[3 * 4 + q] = ghr; sp[4 * 4 + q] = ghz; sp[5 * 4 + q] = ghn;
        }
        __syncthreads();
        if (blk < 64 && (tid & 3) == 0) {
            const int p  = tid >> 2;
            const int jl = p >> 3;
            const int ar = p & 7;
            const int j  = blk * 8 + jl;
            const float* sp = s_part + p * 24;
            float Gir = sp[0]  + sp[1]  + sp[2]  + sp[3];
            float Giz = sp[4]  + sp[5]  + sp[6]  + sp[7];
            float Gin = sp[8]  + sp[9]  + sp[10] + sp[11];
            float Ghr = sp[12] + sp[13] + sp[14] + sp[15];
            float Ghz = sp[16] + sp[17] + sp[18] + sp[19];
            float Ghn = sp[20] + sp[21] + sp[22] + sp[23];
            float ir  = Gir + b_ih[j],         hr_ = Ghr + b_hh[j];
            float iz  = Giz + b_ih[H + j],     hz  = Ghz + b_hh[H + j];
            float inn = Gin + b_ih[2 * H + j], hn  = Ghn + b_hh[2 * H + j];
            float rg = 1.f / (1.f + __expf(-(ir + hr_)));
            float zg = 1.f / (1.f + __expf(-(iz + hz)));
            float ng = tanhf(inn + rg * hn);
            float ho = h_cur[ar * H + j];
            int xr = s_X[ar];
            bool dn = (xr == 0) || (xr == 2);
            h_nxt[ar * H + j] = dn ? ho : ((1.f - zg) * ng + zg * ho);
        }
        gridbar(bar);

        // ---------- phase B: logits + exp + per-block partials --------------
        {
            const float* hrow = h_nxt + r * H;
            const float* w0 = w_out + (size_t)(ok0 ? v_0 : 0) * H;
            const float* w1 = w_out + (size_t)(ok1 ? v_1 : 0) * H;
            float a0 = 0.f, a1 = 0.f;
            for (int k = 0; k < H; k += 4) {
                float4 hv = *(const float4*)(hrow + k);
                a0 += dot4(*(const float4*)(w0 + k), hv);
                a1 += dot4(*(const float4*)(w1 + k), hv);
            }
            e0 = __expf(a0 + b_out[ok0 ? v_0 : 0]);
            e1 = __expf(a1 + b_out[ok1 ? v_1 : 0]);

            float ls = 0.f, bv = -1.f; int bi = 0x7fffffff;
            if (ok0) { ls += e0; if (e0 > bv || (e0 == bv && v_0 < bi)) { bv = e0; bi = v_0; } }
            if (ok1) { ls += e1; if (e1 > bv || (e1 == bv && v_1 < bi)) { bv = e1; bi = v_1; } }
            s_v[tid] = ls; s_av[tid] = bv; s_ai[tid] = bi;
        }
        __syncthreads();
        for (int s = 128; s >= 8; s >>= 1) {   // strides %8==0 keep rows grouped
            if (tid < s) {
                s_v[tid] += s_v[tid + s];
                float ov = s_av[tid + s]; int oi = s_ai[tid + s];
                if (ov > s_av[tid] || (ov == s_av[tid] && oi < s_ai[tid])) {
                    s_av[tid] = ov; s_ai[tid] = oi;
                }
            }
            __syncthreads();
        }
        if (tid < 8) {
            psum[blk * 8 + tid] = s_v[tid];
            pval[blk * 8 + tid] = s_av[tid];
            pidx[blk * 8 + tid] = s_ai[tid];
        }
        gridbar(bar);

        // ---------- phase C: global reduce (redundant per block) + out ------
        {
            const int wv = tid >> 6, lane = tid & 63;
            for (int rr = 0; rr < 2; rr++) {
                const int rw = wv * 2 + rr;
                float s = psum[lane * 8 + rw] + psum[(lane + 64) * 8 + rw]
                        + psum[(lane + 128) * 8 + rw] + psum[(lane + 192) * 8 + rw];
                float bv = pval[lane * 8 + rw]; int bi = pidx[lane * 8 + rw];
#pragma unroll
                for (int c = 1; c < 4; c++) {
                    float ov = pval[(lane + 64 * c) * 8 + rw];
                    int   oi = pidx[(lane + 64 * c) * 8 + rw];
                    if (ov > bv || (ov == bv && oi < bi)) { bv = ov; bi = oi; }
                }
                for (int m = 1; m < 64; m <<= 1) {
                    s += __shfl_xor(s, m, 64);
                    float ov = __shfl_xor(bv, m, 64);
                    int   oi = __shfl_xor(bi, m, 64);
                    if (ov > bv || (ov == bv && oi < bi)) { bv = ov; bi = oi; }
                }
                if (lane == 0) { s_S[rw] = s; s_Xn[rw] = bi; }
            }
        }
        __syncthreads();
        {
            float* out_t = out + (size_t)t * BB * V;
            int xr = s_X[r];                    // OLD x -> done flag for this step
            bool dn = (xr == 0) || (xr == 2);
            float inv = 1.f / s_S[r];
            if (ok0) out_t[r * V + v_0] = dn ? ((v_0 == 0) ? 1.f : 0.f) : e0 * inv;
            if (ok1) out_t[r * V + v_1] = dn ? ((v_1 == 0) ? 1.f : 0.f) : e1 * inv;
        }
        __syncthreads();
        if (tid < 8) {
            int xo = s_X[tid];
            s_X[tid] = ((xo == 0) || (xo == 2)) ? 0 : s_Xn[tid];
        }
        __syncthreads();
    }
}

extern "C" void kernel_launch(void* const* d_in, const int* in_sizes, int n_in,
                              void* d_out, int out_size, void* d_ws, size_t ws_size,
                              hipStream_t stream) {
    (void)in_sizes; (void)n_in; (void)out_size; (void)ws_size;
    const float* hidden    = (const float*)d_in[0];
    const float* embedding = (const float*)d_in[1];
    const float* w_ih      = (const float*)d_in[2];
    const float* w_hh      = (const float*)d_in[3];
    const float* b_ih      = (const float*)d_in[4];
    const float* b_hh      = (const float*)d_in[5];
    const float* w_out     = (const float*)d_in[6];
    const float* b_out     = (const float*)d_in[7];
    float* out = (float*)d_out;

    float* ws   = (float*)d_ws;
    float* hA   = ws;                       // 4096
    float* hB   = hA + BB * H;              // 4096
    float* psum = hB + BB * H;              // NB*8
    float* pval = psum + NB * 8;            // NB*8
    int*   pidx = (int*)(pval + NB * 8);    // NB*8
    int*   bar  = pidx + NB * 8;            // 2

    kinit<<<16, 256, 0, stream>>>(hidden, hA, bar);
    kmain<<<NB, 256, 0, stream>>>(embedding, w_ih, w_hh, b_ih, b_hh, w_out, b_out,
                                  hA, hB, psum, pval, pidx, bar, out);
}

// Round 5
// 726.131 us; speedup vs baseline: 1.9584x; 1.9584x over previous
//
#include <hip/hip_runtime.h>

#define V 16000
#define E 256
#define H 512
#define HP 516     // padded LDS row stride (kills 8-way bank conflicts)
#define BB 8       // batch = greedy rows
#define T 12       // lenseq
#define NB 256     // persistent blocks
#define TPB 512    // threads per block (8 waves -> 2 waves/SIMD)
#define AGENT __HIP_MEMORY_SCOPE_AGENT

// Beam search degenerates to greedy (verified R3: absmax 4.8e-7).
// R4 lesson: __threadfence (agent fence) emits buffer_inv -> L2 invalidated
// every barrier -> w_out (32.8 MB) refetched each step (FETCH 196 MB, 1380us).
// R5: fence-free grid barrier. All cross-block traffic (h, partials, barrier)
// uses agent-scope relaxed/release atomics, which bypass L1/L2 to the IF$
// coherence point -> no cache invalidation, w_out stays L2-resident.

__device__ __forceinline__ float dot4(float4 a, float4 b) {
    return a.x * b.x + a.y * b.y + a.z * b.z + a.w * b.w;
}

__global__ __launch_bounds__(256) void kinit(const float* __restrict__ hidden,
                                             float* __restrict__ hA,
                                             int* __restrict__ bar) {
    int idx = blockIdx.x * 256 + threadIdx.x;
    if (idx < BB * H) hA[idx] = hidden[idx];
    if (idx < 2) bar[idx] = 0;
}

// stage h (BB*H floats, IF$-resident via agent atomics) into padded LDS
__device__ __forceinline__ void stage_h(const float* __restrict__ g,
                                        float* __restrict__ s_h, int tid) {
    int r  = tid >> 6;          // 0..7
    int k0 = (tid & 63) * 8;    // 8 floats per thread
    const unsigned long long* p = (const unsigned long long*)(g + r * H + k0);
    float* d = s_h + r * HP + k0;
#pragma unroll
    for (int i = 0; i < 4; i++) {
        unsigned long long q = __hip_atomic_load(p + i, __ATOMIC_RELAXED, AGENT);
        union { unsigned long long u; float f[2]; } cv; cv.u = q;
        d[2 * i] = cv.f[0]; d[2 * i + 1] = cv.f[1];
    }
}

__device__ __forceinline__ void gridbar(int* bar) {
    __syncthreads();
    if (threadIdx.x == 0) {
        int g = __hip_atomic_load(&bar[1], __ATOMIC_RELAXED, AGENT);
        int old = __hip_atomic_fetch_add(&bar[0], 1, __ATOMIC_RELEASE, AGENT);
        if (old == NB - 1) {
            __hip_atomic_store(&bar[0], 0, __ATOMIC_RELAXED, AGENT);
            __hip_atomic_fetch_add(&bar[1], 1, __ATOMIC_RELEASE, AGENT);
        } else {
            while (__hip_atomic_load(&bar[1], __ATOMIC_RELAXED, AGENT) == g)
                __builtin_amdgcn_s_sleep(1);
        }
    }
    __builtin_amdgcn_fence(__ATOMIC_ACQUIRE, "workgroup");  // compiler order, no L2 inv
    __syncthreads();
}

__global__ __launch_bounds__(TPB) void kmain(
    const float* __restrict__ emb_tab,
    const float* __restrict__ w_ih,
    const float* __restrict__ w_hh,
    const float* __restrict__ b_ih,
    const float* __restrict__ b_hh,
    const float* __restrict__ w_out,
    const float* __restrict__ b_out,
    float* __restrict__ hA,
    float* __restrict__ hB,
    float* __restrict__ psum,   // [2][NB][8] parity double-buffered
    float* __restrict__ pval,
    int* __restrict__ pidx,
    int* __restrict__ bar,
    float* __restrict__ out)
{
    const int blk = blockIdx.x, tid = threadIdx.x;

    __shared__ float s_h[BB * HP];          // 16.5 KB
    __shared__ float s_part[64 * 48];       // 12 KB: 64 pairs x 6 gates x 8 kq
    __shared__ float s_v[TPB];
    __shared__ float s_av[TPB];
    __shared__ int   s_ai[TPB];
    __shared__ float s_S[BB];
    __shared__ int   s_Xn[BB];
    __shared__ int   s_X[BB];

    if (tid < BB) s_X[tid] = 1;             // SOS
    __syncthreads();

    // phase B mapping: 8 lanes (r) share one vocab col
    const int r  = tid & 7;
    const int vl = tid >> 3;                // 0..63
    const int v  = blk * 64 + vl;
    const bool ok = (v < V);
    float e = 0.f;                          // exp(logit), persists B -> C

    for (int t = 0; t < T; t++) {
        const float* h_cur = (t & 1) ? hB : hA;
        float*       h_nxt = (t & 1) ? hA : hB;
        const int par = t & 1;

        // ---------------- phase A: GRU cell (blocks 0..63) ----------------
        if (blk < 64) {
            stage_h(h_cur, s_h, tid);
            __syncthreads();
            const int jl = tid >> 6;        // 0..7
            const int ar = (tid >> 3) & 7;  // row
            const int kq = tid & 7;         // K split 8
            const int j  = blk * 8 + jl;
            const int pair = jl * 8 + ar;
            float gir = 0.f, giz = 0.f, gin = 0.f, ghr = 0.f, ghz = 0.f, ghn = 0.f;
            {
                const float* erow = emb_tab + (size_t)s_X[ar] * E;
                const float* w0 = w_ih + (size_t)j * E;
                const float* w1 = w0 + (size_t)H * E;
                const float* w2 = w1 + (size_t)H * E;
                const int k0 = kq * (E / 8);
                for (int k = k0; k < k0 + E / 8; k += 4) {
                    float4 ev = *(const float4*)(erow + k);
                    gir += dot4(*(const float4*)(w0 + k), ev);
                    giz += dot4(*(const float4*)(w1 + k), ev);
                    gin += dot4(*(const float4*)(w2 + k), ev);
                }
            }
            {
                const float* hrow = s_h + ar * HP;
                const float* w0 = w_hh + (size_t)j * H;
                const float* w1 = w0 + (size_t)H * H;
                const float* w2 = w1 + (size_t)H * H;
                const int k0 = kq * (H / 8);
                for (int k = k0; k < k0 + H / 8; k += 4) {
                    float4 hv = *(const float4*)(hrow + k);
                    ghr += dot4(*(const float4*)(w0 + k), hv);
                    ghz += dot4(*(const float4*)(w1 + k), hv);
                    ghn += dot4(*(const float4*)(w2 + k), hv);
                }
            }
            float* sp = s_part + pair * 48;
            sp[0 * 8 + kq] = gir; sp[1 * 8 + kq] = giz; sp[2 * 8 + kq] = gin;
            sp[3 * 8 + kq] = ghr; sp[4 * 8 + kq] = ghz; sp[5 * 8 + kq] = ghn;
            __syncthreads();
            if (kq == 0) {
                const float* sp2 = s_part + pair * 48;
                float G[6];
#pragma unroll
                for (int gg = 0; gg < 6; gg++) {
                    float s = 0.f;
#pragma unroll
                    for (int q = 0; q < 8; q++) s += sp2[gg * 8 + q];
                    G[gg] = s;
                }
                float ir  = G[0] + b_ih[j],         hr_ = G[3] + b_hh[j];
                float iz  = G[1] + b_ih[H + j],     hz  = G[4] + b_hh[H + j];
                float inn = G[2] + b_ih[2 * H + j], hn  = G[5] + b_hh[2 * H + j];
                float rg = 1.f / (1.f + __expf(-(ir + hr_)));
                float zg = 1.f / (1.f + __expf(-(iz + hz)));
                float ng = tanhf(inn + rg * hn);
                float ho = s_h[ar * HP + j];
                int xr = s_X[ar];
                bool dn = (xr == 0) || (xr == 2);
                float hv = dn ? ho : ((1.f - zg) * ng + zg * ho);
                __hip_atomic_store(&h_nxt[ar * H + j], hv, __ATOMIC_RELAXED, AGENT);
            }
        }
        gridbar(bar);

        // ---------------- phase B: logits + exp + block partials ----------
        stage_h(h_nxt, s_h, tid);
        __syncthreads();
        {
            const float* w  = w_out + (size_t)(ok ? v : 0) * H;
            const float* hr = s_h + r * HP;
            float a0 = 0.f, a1 = 0.f, a2 = 0.f, a3 = 0.f;
            for (int k = 0; k < H; k += 16) {
                float4 w0 = *(const float4*)(w + k);
                float4 w1 = *(const float4*)(w + k + 4);
                float4 w2 = *(const float4*)(w + k + 8);
                float4 w3 = *(const float4*)(w + k + 12);
                float4 h0 = *(const float4*)(hr + k);
                float4 h1 = *(const float4*)(hr + k + 4);
                float4 h2 = *(const float4*)(hr + k + 8);
                float4 h3 = *(const float4*)(hr + k + 12);
                a0 += dot4(w0, h0); a1 += dot4(w1, h1);
                a2 += dot4(w2, h2); a3 += dot4(w3, h3);
            }
            e = __expf(a0 + a1 + a2 + a3 + (ok ? b_out[v] : 0.f));
            s_v[tid]  = ok ? e : 0.f;
            s_av[tid] = ok ? e : -1.f;
            s_ai[tid] = ok ? v : 0x7fffffff;
        }
        __syncthreads();
        for (int s = 256; s >= 8; s >>= 1) {    // strides %8 keep row classes
            if (tid < s) {
                s_v[tid] += s_v[tid + s];
                float ov = s_av[tid + s]; int oi = s_ai[tid + s];
                if (ov > s_av[tid] || (ov == s_av[tid] && oi < s_ai[tid])) {
                    s_av[tid] = ov; s_ai[tid] = oi;
                }
            }
            __syncthreads();
        }
        if (tid < 8) {
            int o = (par * NB + blk) * 8 + tid;
            __hip_atomic_store(&psum[o], s_v[tid],  __ATOMIC_RELAXED, AGENT);
            __hip_atomic_store(&pval[o], s_av[tid], __ATOMIC_RELAXED, AGENT);
            __hip_atomic_store(&pidx[o], s_ai[tid], __ATOMIC_RELAXED, AGENT);
        }
        gridbar(bar);

        // ------- phase C: redundant global reduce + out write + x update ---
        {
            const int rw = tid >> 6;            // wave -> row
            const int lane = tid & 63;
            const int base = par * NB * 8;
            float s = 0.f, bv = -1.f; int bi = 0x7fffffff;
#pragma unroll
            for (int c = 0; c < 4; c++) {
                int o = base + (lane + 64 * c) * 8 + rw;
                s += __hip_atomic_load(&psum[o], __ATOMIC_RELAXED, AGENT);
                float ov = __hip_atomic_load(&pval[o], __ATOMIC_RELAXED, AGENT);
                int   oi = __hip_atomic_load(&pidx[o], __ATOMIC_RELAXED, AGENT);
                if (ov > bv || (ov == bv && oi < bi)) { bv = ov; bi = oi; }
            }
            for (int m = 1; m < 64; m <<= 1) {
                s += __shfl_xor(s, m, 64);
                float ov = __shfl_xor(bv, m, 64);
                int   oi = __shfl_xor(bi, m, 64);
                if (ov > bv || (ov == bv && oi < bi)) { bv = ov; bi = oi; }
            }
            if (lane == 0) { s_S[rw] = s; s_Xn[rw] = bi; }
        }
        __syncthreads();
        {
            float* out_t = out + (size_t)t * BB * V;
            int xr = s_X[r];
            bool dn = (xr == 0) || (xr == 2);
            float inv = 1.f / s_S[r];
            if (ok) {
                float val = dn ? ((v == 0) ? 1.f : 0.f) : e * inv;
                __builtin_nontemporal_store(val, out_t + r * V + v);
            }
        }
        __syncthreads();
        if (tid < 8) {
            int xo = s_X[tid];
            s_X[tid] = ((xo == 0) || (xo == 2)) ? 0 : s_Xn[tid];
        }
        __syncthreads();
    }
}

extern "C" void kernel_launch(void* const* d_in, const int* in_sizes, int n_in,
                              void* d_out, int out_size, void* d_ws, size_t ws_size,
                              hipStream_t stream) {
    (void)in_sizes; (void)n_in; (void)out_size; (void)ws_size;
    const float* hidden    = (const float*)d_in[0];
    const float* embedding = (const float*)d_in[1];
    const float* w_ih      = (const float*)d_in[2];
    const float* w_hh      = (const float*)d_in[3];
    const float* b_ih      = (const float*)d_in[4];
    const float* b_hh      = (const float*)d_in[5];
    const float* w_out     = (const float*)d_in[6];
    const float* b_out     = (const float*)d_in[7];
    float* out = (float*)d_out;

    float* ws   = (float*)d_ws;
    float* hA   = ws;                        // 4096
    float* hB   = hA + BB * H;               // 4096
    float* psum = hB + BB * H;               // 2*NB*8
    float* pval = psum + 2 * NB * 8;         // 2*NB*8
    int*   pidx = (int*)(pval + 2 * NB * 8); // 2*NB*8
    int*   bar  = pidx + 2 * NB * 8;         // 2

    kinit<<<16, 256, 0, stream>>>(hidden, hA, bar);
    kmain<<<NB, TPB, 0, stream>>>(embedding, w_ih, w_hh, b_ih, b_hh, w_out, b_out,
                                  hA, hB, psum, pval, pidx, bar, out);
}

// Round 6
// 617.714 us; speedup vs baseline: 2.3021x; 1.1755x over previous
//
#include <hip/hip_runtime.h>

#define V 16000
#define E 256
#define H 512
#define HP 516     // padded LDS row stride
#define BB 8       // batch = greedy rows
#define T 12       // lenseq
#define NB 256     // persistent blocks
#define TPB 512    // threads per block
#define AGENT __HIP_MEMORY_SCOPE_AGENT

// Greedy degeneracy verified (R3). Persistent kernel since R4.
// R5 lesson: FETCH ~206MB is L2 capacity miss (4MB w_out/XCD in 4MB L2), but
// the dominant ~500us was the CENTRAL barrier: 256 same-address atomic RMWs
// + same-line spin polls serialize at the coherence point (~20us/barrier x24).
// R6: distributed barrier. Arrival via 64 padded per-group counters
// (4 blocks each, monotonic epoch targets - no reset race); last arriver sets
// flag[g]=ep; everyone polls the 64-word flag array with one coalesced lane
// load + __all ballot. Partials re-laid [parity][row][NB] for coalesced
// phase-C reads. Kernel body otherwise identical to R5.

__device__ __forceinline__ float dot4(float4 a, float4 b) {
    return a.x * b.x + a.y * b.y + a.z * b.z + a.w * b.w;
}

__global__ __launch_bounds__(256) void kinit(const float* __restrict__ hidden,
                                             float* __restrict__ hA,
                                             int* __restrict__ cnt,
                                             int* __restrict__ flag) {
    int idx = blockIdx.x * 256 + threadIdx.x;
    if (idx < BB * H) hA[idx] = hidden[idx];
    if (idx < 64 * 16) cnt[idx] = 0;     // padded group counters
    if (idx < 64) flag[idx] = 0;         // group flags
}

// stage h (IF$-resident via agent atomics) into padded LDS
__device__ __forceinline__ void stage_h(const float* __restrict__ g,
                                        float* __restrict__ s_h, int tid) {
    int r  = tid >> 6;          // 0..7
    int k0 = (tid & 63) * 8;    // 8 floats per thread
    const unsigned long long* p = (const unsigned long long*)(g + r * H + k0);
    float* d = s_h + r * HP + k0;
#pragma unroll
    for (int i = 0; i < 4; i++) {
        unsigned long long q = __hip_atomic_load(p + i, __ATOMIC_RELAXED, AGENT);
        union { unsigned long long u; float f[2]; } cv; cv.u = q;
        d[2 * i] = cv.f[0]; d[2 * i + 1] = cv.f[1];
    }
}

__device__ __forceinline__ void gridbar(int* __restrict__ cnt,
                                        int* __restrict__ flag, int ep) {
    __syncthreads();
    if (threadIdx.x == 0) {
        int g = blockIdx.x >> 2;                       // group of 4 blocks
        int old = __hip_atomic_fetch_add(&cnt[g * 16], 1, __ATOMIC_RELEASE, AGENT);
        if (old == 4 * ep - 1)                         // monotonic: no reset
            __hip_atomic_store(&flag[g], ep, __ATOMIC_RELAXED, AGENT);
    }
    if (threadIdx.x < 64) {                            // wave 0: coalesced poll
        while (!__all(__hip_atomic_load(&flag[threadIdx.x],
                                        __ATOMIC_RELAXED, AGENT) >= ep))
            __builtin_amdgcn_s_sleep(2);
    }
    __builtin_amdgcn_fence(__ATOMIC_ACQUIRE, "workgroup");  // compiler order only
    __syncthreads();
}

__global__ __launch_bounds__(TPB) void kmain(
    const float* __restrict__ emb_tab,
    const float* __restrict__ w_ih,
    const float* __restrict__ w_hh,
    const float* __restrict__ b_ih,
    const float* __restrict__ b_hh,
    const float* __restrict__ w_out,
    const float* __restrict__ b_out,
    float* __restrict__ hA,
    float* __restrict__ hB,
    float* __restrict__ psum,   // [2][8][NB]
    float* __restrict__ pval,
    int* __restrict__ pidx,
    int* __restrict__ cnt,
    int* __restrict__ flag,
    float* __restrict__ out)
{
    const int blk = blockIdx.x, tid = threadIdx.x;

    __shared__ float s_h[BB * HP];          // 16.5 KB
    __shared__ float s_part[64 * 48];       // 12 KB
    __shared__ float s_v[TPB];
    __shared__ float s_av[TPB];
    __shared__ int   s_ai[TPB];
    __shared__ float s_S[BB];
    __shared__ int   s_Xn[BB];
    __shared__ int   s_X[BB];

    if (tid < BB) s_X[tid] = 1;             // SOS
    __syncthreads();

    const int r  = tid & 7;
    const int vl = tid >> 3;                // 0..63
    const int v  = blk * 64 + vl;
    const bool ok = (v < V);
    float e = 0.f;                          // exp(logit), persists B -> C

    for (int t = 0; t < T; t++) {
        const float* h_cur = (t & 1) ? hB : hA;
        float*       h_nxt = (t & 1) ? hA : hB;
        const int par = t & 1;

        // ---------------- phase A: GRU cell (blocks 0..63) ----------------
        if (blk < 64) {
            stage_h(h_cur, s_h, tid);
            __syncthreads();
            const int jl = tid >> 6;        // 0..7
            const int ar = (tid >> 3) & 7;  // row
            const int kq = tid & 7;         // K split 8
            const int j  = blk * 8 + jl;
            const int pair = jl * 8 + ar;
            float gir = 0.f, giz = 0.f, gin = 0.f, ghr = 0.f, ghz = 0.f, ghn = 0.f;
            {
                const float* erow = emb_tab + (size_t)s_X[ar] * E;
                const float* w0 = w_ih + (size_t)j * E;
                const float* w1 = w0 + (size_t)H * E;
                const float* w2 = w1 + (size_t)H * E;
                const int k0 = kq * (E / 8);
                for (int k = k0; k < k0 + E / 8; k += 4) {
                    float4 ev = *(const float4*)(erow + k);
                    gir += dot4(*(const float4*)(w0 + k), ev);
                    giz += dot4(*(const float4*)(w1 + k), ev);
                    gin += dot4(*(const float4*)(w2 + k), ev);
                }
            }
            {
                const float* hrow = s_h + ar * HP;
                const float* w0 = w_hh + (size_t)j * H;
                const float* w1 = w0 + (size_t)H * H;
                const float* w2 = w1 + (size_t)H * H;
                const int k0 = kq * (H / 8);
                for (int k = k0; k < k0 + H / 8; k += 4) {
                    float4 hv = *(const float4*)(hrow + k);
                    ghr += dot4(*(const float4*)(w0 + k), hv);
                    ghz += dot4(*(const float4*)(w1 + k), hv);
                    ghn += dot4(*(const float4*)(w2 + k), hv);
                }
            }
            float* sp = s_part + pair * 48;
            sp[0 * 8 + kq] = gir; sp[1 * 8 + kq] = giz; sp[2 * 8 + kq] = gin;
            sp[3 * 8 + kq] = ghr; sp[4 * 8 + kq] = ghz; sp[5 * 8 + kq] = ghn;
            __syncthreads();
            if (kq == 0) {
                const float* sp2 = s_part + pair * 48;
                float G[6];
#pragma unroll
                for (int gg = 0; gg < 6; gg++) {
                    float s = 0.f;
#pragma unroll
                    for (int q = 0; q < 8; q++) s += sp2[gg * 8 + q];
                    G[gg] = s;
                }
                float ir  = G[0] + b_ih[j],         hr_ = G[3] + b_hh[j];
                float iz  = G[1] + b_ih[H + j],     hz  = G[4] + b_hh[H + j];
                float inn = G[2] + b_ih[2 * H + j], hn  = G[5] + b_hh[2 * H + j];
                float rg = 1.f / (1.f + __expf(-(ir + hr_)));
                float zg = 1.f / (1.f + __expf(-(iz + hz)));
                float ng = tanhf(inn + rg * hn);
                float ho = s_h[ar * HP + j];
                int xr = s_X[ar];
                bool dn = (xr == 0) || (xr == 2);
                float hv = dn ? ho : ((1.f - zg) * ng + zg * ho);
                __hip_atomic_store(&h_nxt[ar * H + j], hv, __ATOMIC_RELAXED, AGENT);
            }
        }
        gridbar(cnt, flag, 2 * t + 1);

        // ---------------- phase B: logits + exp + block partials ----------
        stage_h(h_nxt, s_h, tid);
        __syncthreads();
        {
            const float* w  = w_out + (size_t)(ok ? v : 0) * H;
            const float* hr = s_h + r * HP;
            float a0 = 0.f, a1 = 0.f, a2 = 0.f, a3 = 0.f;
            for (int k = 0; k < H; k += 16) {
                float4 w0 = *(const float4*)(w + k);
                float4 w1 = *(const float4*)(w + k + 4);
                float4 w2 = *(const float4*)(w + k + 8);
                float4 w3 = *(const float4*)(w + k + 12);
                float4 h0 = *(const float4*)(hr + k);
                float4 h1 = *(const float4*)(hr + k + 4);
                float4 h2 = *(const float4*)(hr + k + 8);
                float4 h3 = *(const float4*)(hr + k + 12);
                a0 += dot4(w0, h0); a1 += dot4(w1, h1);
                a2 += dot4(w2, h2); a3 += dot4(w3, h3);
            }
            e = __expf(a0 + a1 + a2 + a3 + (ok ? b_out[v] : 0.f));
            s_v[tid]  = ok ? e : 0.f;
            s_av[tid] = ok ? e : -1.f;
            s_ai[tid] = ok ? v : 0x7fffffff;
        }
        __syncthreads();
        for (int s = 256; s >= 8; s >>= 1) {
            if (tid < s) {
                s_v[tid] += s_v[tid + s];
                float ov = s_av[tid + s]; int oi = s_ai[tid + s];
                if (ov > s_av[tid] || (ov == s_av[tid] && oi < s_ai[tid])) {
                    s_av[tid] = ov; s_ai[tid] = oi;
                }
            }
            __syncthreads();
        }
        if (tid < 8) {
            int o = (par * 8 + tid) * NB + blk;    // [par][row][blk]
            __hip_atomic_store(&psum[o], s_v[tid],  __ATOMIC_RELAXED, AGENT);
            __hip_atomic_store(&pval[o], s_av[tid], __ATOMIC_RELAXED, AGENT);
            __hip_atomic_store(&pidx[o], s_ai[tid], __ATOMIC_RELAXED, AGENT);
        }
        gridbar(cnt, flag, 2 * t + 2);

        // ------- phase C: redundant global reduce + out write + x update ---
        {
            const int rw = tid >> 6;            // wave -> row
            const int lane = tid & 63;
            const int base = (par * 8 + rw) * NB;
            float s = 0.f, bv = -1.f; int bi = 0x7fffffff;
#pragma unroll
            for (int c = 0; c < 4; c++) {       // coalesced: lane-contiguous
                int o = base + lane + 64 * c;
                s += __hip_atomic_load(&psum[o], __ATOMIC_RELAXED, AGENT);
                float ov = __hip_atomic_load(&pval[o], __ATOMIC_RELAXED, AGENT);
                int   oi = __hip_atomic_load(&pidx[o], __ATOMIC_RELAXED, AGENT);
                if (ov > bv || (ov == bv && oi < bi)) { bv = ov; bi = oi; }
            }
            for (int m = 1; m < 64; m <<= 1) {
                s += __shfl_xor(s, m, 64);
                float ov = __shfl_xor(bv, m, 64);
                int   oi = __shfl_xor(bi, m, 64);
                if (ov > bv || (ov == bv && oi < bi)) { bv = ov; bi = oi; }
            }
            if (lane == 0) { s_S[rw] = s; s_Xn[rw] = bi; }
        }
        __syncthreads();
        {
            float* out_t = out + (size_t)t * BB * V;
            int xr = s_X[r];
            bool dn = (xr == 0) || (xr == 2);
            float inv = 1.f / s_S[r];
            if (ok) {
                float val = dn ? ((v == 0) ? 1.f : 0.f) : e * inv;
                __builtin_nontemporal_store(val, out_t + r * V + v);
            }
        }
        __syncthreads();
        if (tid < 8) {
            int xo = s_X[tid];
            s_X[tid] = ((xo == 0) || (xo == 2)) ? 0 : s_Xn[tid];
        }
        __syncthreads();
    }
}

extern "C" void kernel_launch(void* const* d_in, const int* in_sizes, int n_in,
                              void* d_out, int out_size, void* d_ws, size_t ws_size,
                              hipStream_t stream) {
    (void)in_sizes; (void)n_in; (void)out_size; (void)ws_size;
    const float* hidden    = (const float*)d_in[0];
    const float* embedding = (const float*)d_in[1];
    const float* w_ih      = (const float*)d_in[2];
    const float* w_hh      = (const float*)d_in[3];
    const float* b_ih      = (const float*)d_in[4];
    const float* b_hh      = (const float*)d_in[5];
    const float* w_out     = (const float*)d_in[6];
    const float* b_out     = (const float*)d_in[7];
    float* out = (float*)d_out;

    float* ws   = (float*)d_ws;
    float* hA   = ws;                        // 4096
    float* hB   = hA + BB * H;               // 4096
    float* psum = hB + BB * H;               // 2*8*NB
    float* pval = psum + 2 * 8 * NB;         // 2*8*NB
    int*   pidx = (int*)(pval + 2 * 8 * NB); // 2*8*NB
    int*   cnt  = pidx + 2 * 8 * NB;         // 64*16 padded counters
    int*   flag = cnt + 64 * 16;             // 64 flags

    kinit<<<16, 256, 0, stream>>>(hidden, hA, cnt, flag);
    kmain<<<NB, TPB, 0, stream>>>(embedding, w_ih, w_hh, b_ih, b_hh, w_out, b_out,
                                  hA, hB, psum, pval, pidx, cnt, flag, out);
}